// Round 6
// baseline (132.539 us; speedup 1.0000x reference)
//
#include <hip/hip_runtime.h>
#include <math.h>

#define NB 32
#define CC 512
#define NJ 10

__device__ __forceinline__ float wave_reduce(float s) {
#pragma unroll
  for (int off = 32; off; off >>= 1) s += __shfl_down(s, off, 64);
  return s;
}

// K1: gap[n,c] = mean_p x[n,c,p]. 1024 blocks x 256 thr; wave owns 4 rows,
// all 16 float4 loads issued before any reduce (latency overlap).
__global__ __launch_bounds__(256) void k_gap(const float* __restrict__ x,
                                             float* __restrict__ gap) {
  int wv = threadIdx.x >> 6, lane = threadIdx.x & 63;
  int r0 = blockIdx.x * 16 + wv * 4;
  float4 v[4][4];
#pragma unroll
  for (int it = 0; it < 4; ++it) {
    const float4* xp = (const float4*)x + (size_t)(r0 + it) * 256;
#pragma unroll
    for (int k = 0; k < 4; ++k) v[it][k] = xp[lane + 64 * k];
  }
#pragma unroll
  for (int it = 0; it < 4; ++it) {
    float s = 0.f;
#pragma unroll
    for (int k = 0; k < 4; ++k)
      s += v[it][k].x + v[it][k].y + v[it][k].z + v[it][k].w;
    s = wave_reduce(s);
    if (lane == 0) gap[r0 + it] = s * (1.0f / 1024.0f);
  }
}

// K2: per batch n: q = sigmoid(conv5(gap)+b); coef[n][j] = (1/j!)/Z,
// Z = sum_j P_j^2/j!, P_j = sum_c q_c^j.  32 blocks x 512 threads.
__global__ __launch_bounds__(512) void k_q(const float* __restrict__ gap,
                                           const float* __restrict__ wq,
                                           const float* __restrict__ bq,
                                           float* __restrict__ q,
                                           float* __restrict__ coef) {
  int n = blockIdx.x, c = threadIdx.x;
  int wv = c >> 6, lane = c & 63;
  __shared__ float wred[8][NJ];
  const float cj[NJ] = {1.f, 1.f, 0.5f, 1.f / 6.f, 1.f / 24.f, 1.f / 120.f,
                        1.f / 720.f, 1.f / 5040.f, 1.f / 40320.f, 1.f / 362880.f};
  const float* g = gap + n * CC;
  float z = bq[0];
#pragma unroll
  for (int k = 0; k < 5; ++k) {
    int idx = c + k - 2;
    float gv = (idx >= 0 && idx < CC) ? g[idx] : 0.f;
    z = fmaf(gv, wq[k], z);
  }
  float qv = 1.f / (1.f + expf(-z));
  q[n * CC + c] = qv;
  float pj[NJ];
  float pw = 1.f;
#pragma unroll
  for (int j = 0; j < NJ; ++j) { pj[j] = pw; pw *= qv; }
#pragma unroll
  for (int j = 0; j < NJ; ++j) pj[j] = wave_reduce(pj[j]);
  if (lane == 0) {
#pragma unroll
    for (int j = 0; j < NJ; ++j) wred[wv][j] = pj[j];
  }
  __syncthreads();
  if (c == 0) {
    float Z = 0.f;
    float P[NJ];
#pragma unroll
    for (int j = 0; j < NJ; ++j) {
      float p = 0.f;
#pragma unroll
      for (int w8 = 0; w8 < 8; ++w8) p += wred[w8][j];
      P[j] = p;
      Z = fmaf(cj[j] * p, p, Z);
    }
    float iz = 1.f / Z;
#pragma unroll
    for (int j = 0; j < NJ; ++j) coef[n * NJ + j] = cj[j] * iz;
  }
}

// K3: fused moments + output. 512 blocks (n, pblk of 64 p) x 512 threads,
// 2 blocks/CU (launch_bounds(512,2) -> 128-VGPR cap; demand ~115, no spill).
// Thread (cg,pg): xv[16] = x[cg*16..+15][pblk*64+pg*4..+3], read once.
//  B: acc_j = sum_i q^j xv[i] (two j-halves of 5, acc=20 VGPRs)
//     shfl over cg + LDS tree -> sfin[pg][j] = coef_j * s_j
//  C: out = xv[i] * sum_j sfin[pg][j] q_d^j
__global__ __launch_bounds__(512, 2) void k_out(const float* __restrict__ x,
                                                const float* __restrict__ q,
                                                const float* __restrict__ coef,
                                                float* __restrict__ out) {
  int n = blockIdx.x >> 4, pblk = blockIdx.x & 15;
  int t = threadIdx.x;
  int cg = t >> 4, pg = t & 15;
  int wv = t >> 6, lane = t & 63;

  __shared__ float qs[CC];
  __shared__ float cf[NJ];
  __shared__ float4 sred[8][16][NJ + 1];
  __shared__ float4 sfin[16][NJ + 1];

  // stage q + coef
  qs[t] = q[n * CC + t];
  if (t < NJ) cf[t] = coef[n * NJ + t];

  // load x tile (only read of x in this kernel)
  float4 xv[16];
  const float4* x4 = (const float4*)x;
  size_t base = (size_t)(n * CC + cg * 16) * 256 + (size_t)pblk * 16 + pg;
#pragma unroll
  for (int i = 0; i < 16; ++i) xv[i] = x4[base + (size_t)i * 256];
  __syncthreads();  // qs/cf visible

  // phase B: moments in two j-halves (VGPR cap 128)
#pragma unroll
  for (int half = 0; half < 2; ++half) {
    float4 acc[5];
#pragma unroll
    for (int j = 0; j < 5; ++j) acc[j] = make_float4(0.f, 0.f, 0.f, 0.f);
#pragma unroll
    for (int i = 0; i < 16; ++i) {
      float qc = qs[cg * 16 + i];
      float4 v = xv[i];
      float w;
      if (half == 0) w = 1.f;
      else { float q2 = qc * qc; w = q2 * q2 * qc; }  // qc^5
#pragma unroll
      for (int j = 0; j < 5; ++j) {
        acc[j].x = fmaf(w, v.x, acc[j].x);
        acc[j].y = fmaf(w, v.y, acc[j].y);
        acc[j].z = fmaf(w, v.z, acc[j].z);
        acc[j].w = fmaf(w, v.w, acc[j].w);
        w *= qc;
      }
    }
    // combine the wave's 4 channel-groups (lane bits 4,5)
#pragma unroll
    for (int j = 0; j < 5; ++j) {
      acc[j].x += __shfl_xor(acc[j].x, 16, 64);
      acc[j].y += __shfl_xor(acc[j].y, 16, 64);
      acc[j].z += __shfl_xor(acc[j].z, 16, 64);
      acc[j].w += __shfl_xor(acc[j].w, 16, 64);
      acc[j].x += __shfl_xor(acc[j].x, 32, 64);
      acc[j].y += __shfl_xor(acc[j].y, 32, 64);
      acc[j].z += __shfl_xor(acc[j].z, 32, 64);
      acc[j].w += __shfl_xor(acc[j].w, 32, 64);
    }
    if (lane < 16) {
#pragma unroll
      for (int j = 0; j < 5; ++j) sred[wv][lane][half * 5 + j] = acc[j];
    }
  }
  __syncthreads();
  if (t < 160) {  // 16 pg x 10 j; fold in coef_j (has invZ and 1/j!)
    int pp = t / NJ, j = t - pp * NJ;
    float4 a = make_float4(0.f, 0.f, 0.f, 0.f);
#pragma unroll
    for (int w8 = 0; w8 < 8; ++w8) {
      float4 v = sred[w8][pp][j];
      a.x += v.x; a.y += v.y; a.z += v.z; a.w += v.w;
    }
    float sc = cf[j];
    a.x *= sc; a.y *= sc; a.z *= sc; a.w *= sc;
    sfin[pp][j] = a;
  }
  __syncthreads();

  // phase C: output from register-held x
  float4 sj[NJ];
#pragma unroll
  for (int j = 0; j < NJ; ++j) sj[j] = sfin[pg][j];
  float4* o4 = (float4*)out;
#pragma unroll
  for (int i = 0; i < 16; ++i) {
    float qd = qs[cg * 16 + i];
    float w = 1.f;
    float4 att = make_float4(0.f, 0.f, 0.f, 0.f);
#pragma unroll
    for (int j = 0; j < NJ; ++j) {
      att.x = fmaf(w, sj[j].x, att.x);
      att.y = fmaf(w, sj[j].y, att.y);
      att.z = fmaf(w, sj[j].z, att.z);
      att.w = fmaf(w, sj[j].w, att.w);
      w *= qd;
    }
    float4 xvv = xv[i];
    float4 o;
    o.x = xvv.x * att.x; o.y = xvv.y * att.y;
    o.z = xvv.z * att.z; o.w = xvv.w * att.w;
    o4[base + (size_t)i * 256] = o;
  }
}

extern "C" void kernel_launch(void* const* d_in, const int* in_sizes, int n_in,
                              void* d_out, int out_size, void* d_ws, size_t ws_size,
                              hipStream_t stream) {
  const float* x  = (const float*)d_in[0];
  const float* wq = (const float*)d_in[1];
  const float* bq = (const float*)d_in[2];
  float* out = (float*)d_out;
  char* ws = (char*)d_ws;

  float* gap  = (float*)(ws);            // 64 KB, fully written by k_gap
  float* q    = (float*)(ws + 65536);    // 64 KB, fully written by k_q
  float* coef = (float*)(ws + 131072);   // 32*10 floats, fully written by k_q

  k_gap<<<NB * CC / 16, 256, 0, stream>>>(x, gap);
  k_q<<<NB, 512, 0, stream>>>(gap, wq, bq, q, coef);
  k_out<<<NB * 16, 512, 0, stream>>>(x, q, coef, out);
}